// Round 10
// baseline (476.304 us; speedup 1.0000x reference)
//
#include <hip/hip_runtime.h>
#include <hip/hip_bf16.h>

#define N_NODES 8192
#define D_FEAT 128

typedef __bf16 bf16x8 __attribute__((ext_vector_type(8)));
typedef float f32x4 __attribute__((ext_vector_type(4)));

// lgkm-only barrier: real compiler fence, no vmcnt drain (R8-verified, -22us).
__device__ __forceinline__ void lgkm_barrier() {
  asm volatile("s_waitcnt lgkmcnt(0)\n\ts_barrier" ::: "memory");
}

// ---- cold path: on-the-fly LSH band-collision check (never taken for the
// given Gaussian inputs: max off-diag cosine ~0.49 << 0.75).
__device__ __attribute__((noinline)) bool lsh_collide(
    const float* __restrict__ z, const float* __restrict__ H, int i, int j) {
  for (int b = 0; b < 64; ++b) {          // 64 bands x 8 bits
    unsigned ci = 0, cj = 0;
    for (int bit = 0; bit < 8; ++bit) {
      int col = b * 8 + bit;
      float di = 0.f, dj = 0.f;
      for (int k = 0; k < D_FEAT; ++k) {
        float h = H[(size_t)k * 512 + col];
        di += z[(size_t)i * D_FEAT + k] * h;
        dj += z[(size_t)j * D_FEAT + k] * h;
      }
      if (di > 0.f) ci |= (1u << bit);
      if (dj > 0.f) cj |= (1u << bit);
    }
    if (ci == cj) return true;
  }
  return false;
}

__device__ __forceinline__ unsigned pack_bf16x2(float x, float y) {
  __hip_bfloat16 bx = __float2bfloat16(x), by = __float2bfloat16(y);
  return (unsigned)(*(unsigned short*)&bx) |
         ((unsigned)(*(unsigned short*)&by) << 16);
}

// Stage 128 z-rows (B tile), 256 threads: 2 threads/row (R4/R8-verified).
__device__ __forceinline__ void stage_tile128(const float* __restrict__ z, int blk,
                                              unsigned short (*T)[128], int tid) {
  int row = tid >> 1, half = tid & 1;
  const float4* src = (const float4*)(z + (size_t)(blk * 128 + row) * D_FEAT + half * 64);
  float4 v[16];
#pragma unroll
  for (int c = 0; c < 16; ++c) v[c] = src[c];
  float ss = 0.f;
#pragma unroll
  for (int c = 0; c < 16; ++c)
    ss += v[c].x * v[c].x + v[c].y * v[c].y + v[c].z * v[c].z + v[c].w * v[c].w;
  ss += __shfl_xor(ss, 1);
  float inv = rsqrtf(ss);
#pragma unroll
  for (int c = 0; c < 8; ++c) {
    float4 a = v[2 * c], b = v[2 * c + 1];
    uint4 o;
    o.x = pack_bf16x2(a.x * inv, a.y * inv);
    o.y = pack_bf16x2(a.z * inv, a.w * inv);
    o.z = pack_bf16x2(b.x * inv, b.y * inv);
    o.w = pack_bf16x2(b.z * inv, b.w * inv);
    ((uint4*)&T[row][0])[(half * 8 + c) ^ (row & 15)] = o;
  }
}

// Stage 64 z-rows (A tile), 256 threads: 4 threads/row (R5/R9-verified).
__device__ __forceinline__ void stage_tile64(const float* __restrict__ z, int row0,
                                             unsigned short (*T)[128], int tid) {
  int row = tid >> 2, q = tid & 3;
  const float4* src = (const float4*)(z + (size_t)(row0 + row) * D_FEAT + q * 32);
  float4 v[8];
#pragma unroll
  for (int c = 0; c < 8; ++c) v[c] = src[c];
  float ss = 0.f;
#pragma unroll
  for (int c = 0; c < 8; ++c)
    ss += v[c].x * v[c].x + v[c].y * v[c].y + v[c].z * v[c].z + v[c].w * v[c].w;
  ss += __shfl_xor(ss, 1);
  ss += __shfl_xor(ss, 2);
  float inv = rsqrtf(ss);
#pragma unroll
  for (int c = 0; c < 4; ++c) {
    float4 a = v[2 * c], b = v[2 * c + 1];
    uint4 o;
    o.x = pack_bf16x2(a.x * inv, a.y * inv);
    o.y = pack_bf16x2(a.z * inv, a.w * inv);
    o.z = pack_bf16x2(b.x * inv, b.y * inv);
    o.w = pack_bf16x2(b.z * inv, b.w * inv);
    ((uint4*)&T[row][0])[(q * 4 + c) ^ (row & 15)] = o;
  }
}

// Store the 64x128 fp32 tile in fS to out (store waves, 256 threads).
// 8 dwordx4 per thread; 32 consecutive lanes cover one full 512B row.
__device__ __forceinline__ void store_fs(float* __restrict__ out,
                                         const float* __restrict__ fS,
                                         int bm, int bn, int st) {
#pragma unroll
  for (int it = 0; it < 8; ++it) {
    int slot = st + 256 * it;             // 0..2047 float4 slots
    int row = slot >> 5, chunk = slot & 31;
    f32x4 v = *(const f32x4*)&fS[row * 128 + ((chunk ^ (row & 31)) << 2)];
    *(f32x4*)&out[(size_t)(bm * 64 + row) * N_NODES + bn * 128 + chunk * 4] = v;
  }
}

// Producer/consumer persistent kernel. 512 threads: waves 0-3 compute
// (stage/MFMA/epilogue->fS), waves 4-7 store (fS->out, NO loads => their
// vmcnt FIFO never forces a store drain; deep store queue keeps the HBM
// write pipe busy while compute waves run). Separate waves = separate
// vmcnt FIFOs — breaks the in-order load-behind-store serialization that
// made R8/R9 run at store+compute SERIAL time (~58us vs 41us floor).
// LDS 80 KB (As 16 + Bs 32 persistent + fS 32, disjoint) -> 2 blocks/CU.
__global__ __launch_bounds__(512, 4) void sim_kernel(const float* __restrict__ z,
                                                     const float* __restrict__ H,
                                                     float* __restrict__ out) {
  __shared__ __align__(16) unsigned char smem_raw[81920];
  unsigned short (*As)[128] = (unsigned short (*)[128])smem_raw;            // 64 rows, 16 KB
  unsigned short (*Bs)[128] = (unsigned short (*)[128])(smem_raw + 16384);  // 128 rows, 32 KB persistent
  float* fS = (float*)(smem_raw + 49152);                                   // 64x128 fp32, 32 KB

  int tid = threadIdx.x;
  int b = (int)blockIdx.x;
  int bn = b & 63;
  int bm0 = b >> 6;                // 0..7 -> 16 rounds each

  int wv = tid >> 6;
  bool is_store = wv >= 4;
  int st = tid & 255;              // role-local tid (0..255)

  int cw = wv & 3, lane = tid & 63;
  int wm = (cw >> 1) * 32, wn = (cw & 1) * 64;
  int m16 = lane & 15, g = lane >> 4;

  if (!is_store) stage_tile128(z, bn, Bs, st);   // Bs resident for all rounds

  for (int t = 0; t < 16; ++t) {
    int bm = bm0 * 16 + t;

    // (1) fS(t-1) writes visible; As(t-1) frag reads done.
    lgkm_barrier();
    if (!is_store) {
      stage_tile64(z, bm * 64, As, st);
    } else if (t > 0) {
      store_fs(out, fS, bm - 1, bn, st);   // stores fire; never waited on
    }
    // (2) As(t) staged visible to all compute waves; fS(t-1) ds_reads done.
    lgkm_barrier();

    if (!is_store) {
      // ---- MFMA: 32x64 quadrant, 2x4 tiles of 16x16x32, K=128 ----
      f32x4 acc[2][4] = {};
#pragma unroll
      for (int kc = 0; kc < 4; ++kc) {
        bf16x8 fa[2], fb[4];
        int chunk = kc * 4 + g;
        int cs = (chunk ^ m16) * 8;   // row bases multiples of 16 -> row&15 == m16
#pragma unroll
        for (int tt = 0; tt < 2; ++tt) fa[tt] = *(const bf16x8*)&As[wm + tt * 16 + m16][cs];
#pragma unroll
        for (int tt = 0; tt < 4; ++tt) fb[tt] = *(const bf16x8*)&Bs[wn + tt * 16 + m16][cs];
#pragma unroll
        for (int tm = 0; tm < 2; ++tm)
#pragma unroll
          for (int tn = 0; tn < 4; ++tn)
            acc[tm][tn] = __builtin_amdgcn_mfma_f32_16x16x32_bf16(fa[tm], fb[tn], acc[tm][tn], 0, 0, 0);
      }

      // ---- epilogue: C-layout (col=lane&15, row=g*4+r) -> swizzled fS ----
#pragma unroll
      for (int tm = 0; tm < 2; ++tm) {
#pragma unroll
        for (int tn = 0; tn < 4; ++tn) {
          int col = wn + tn * 16 + m16;   // tile-local col 0..127
          int j = bn * 128 + col;
          f32x4 c = acc[tm][tn];
#pragma unroll
          for (int r = 0; r < 4; ++r) {
            int row = wm + tm * 16 + g * 4 + r;   // tile-local row 0..63
            int i = bm * 64 + row;
            float s = c[r];
            float val = 0.0f;
            if (i == j) {
              val = 1.0f;
            } else if (s > 0.75f) {
              if (lsh_collide(z, H, i, j)) val = s;   // cold path
            }
            fS[row * 128 + ((((col >> 2) ^ (row & 31)) << 2) | (col & 3))] = val;
          }
        }
      }
    }
  }

  // tail: store the final round's tile
  lgkm_barrier();
  if (is_store) store_fs(out, fS, bm0 * 16 + 15, bn, st);
}

extern "C" void kernel_launch(void* const* d_in, const int* in_sizes, int n_in,
                              void* d_out, int out_size, void* d_ws, size_t ws_size,
                              hipStream_t stream) {
  const float* z = (const float*)d_in[0];   // [8192, 128] fp32
  const float* H = (const float*)d_in[1];   // [128, 512] fp32
  // d_in[2] = edge_index, unused by the reference forward.
  float* out = (float*)d_out;               // [8192, 8192] fp32
  (void)d_ws; (void)ws_size;

  sim_kernel<<<512, 512, 0, stream>>>(z, H, out);
}

// Round 11
// 278.236 us; speedup vs baseline: 1.7119x; 1.7119x over previous
//
#include <hip/hip_runtime.h>
#include <hip/hip_bf16.h>

#define N_NODES 8192
#define D_FEAT 128

typedef __bf16 bf16x8 __attribute__((ext_vector_type(8)));
typedef float f32x4 __attribute__((ext_vector_type(4)));

// Barrier that waits ONLY on LDS ops (lgkmcnt(0)) — does NOT drain vmcnt,
// so global stores issued before it stay in flight across the barrier.
// Inline asm with "memory" clobber = real compiler fence (R8-verified, -22us;
// R7's builtin version was NOT a compiler fence and miscompiled).
__device__ __forceinline__ void lgkm_barrier() {
  asm volatile("s_waitcnt lgkmcnt(0)\n\ts_barrier" ::: "memory");
}
// Wave-local LDS write->read ordering point (no cross-wave barrier needed).
__device__ __forceinline__ void lgkm_fence() {
  asm volatile("s_waitcnt lgkmcnt(0)" ::: "memory");
}

// ---- cold path: on-the-fly LSH band-collision check (never taken for the
// given Gaussian inputs: max off-diag cosine ~0.49 << 0.75).
__device__ __attribute__((noinline)) bool lsh_collide(
    const float* __restrict__ z, const float* __restrict__ H, int i, int j) {
  for (int b = 0; b < 64; ++b) {          // 64 bands x 8 bits
    unsigned ci = 0, cj = 0;
    for (int bit = 0; bit < 8; ++bit) {
      int col = b * 8 + bit;
      float di = 0.f, dj = 0.f;
      for (int k = 0; k < D_FEAT; ++k) {
        float h = H[(size_t)k * 512 + col];
        di += z[(size_t)i * D_FEAT + k] * h;
        dj += z[(size_t)j * D_FEAT + k] * h;
      }
      if (di > 0.f) ci |= (1u << bit);
      if (dj > 0.f) cj |= (1u << bit);
    }
    if (ci == cj) return true;
  }
  return false;
}

__device__ __forceinline__ unsigned pack_bf16x2(float x, float y) {
  __hip_bfloat16 bx = __float2bfloat16(x), by = __float2bfloat16(y);
  return (unsigned)(*(unsigned short*)&bx) |
         ((unsigned)(*(unsigned short*)&by) << 16);
}

// Normalize 128 z-rows of block `blk` into bf16 tile T (XOR-swizzled 16B
// chunks). 2 threads/row, pair-shuffle reduce. (R4/R8-verified.)
__device__ __forceinline__ void stage_tile(const float* __restrict__ z, int blk,
                                           unsigned short (*T)[128], int tid) {
  int row = tid >> 1, half = tid & 1;
  const float4* src = (const float4*)(z + (size_t)(blk * 128 + row) * D_FEAT + half * 64);
  float4 v[16];
#pragma unroll
  for (int c = 0; c < 16; ++c) v[c] = src[c];
  float ss = 0.f;
#pragma unroll
  for (int c = 0; c < 16; ++c)
    ss += v[c].x * v[c].x + v[c].y * v[c].y + v[c].z * v[c].z + v[c].w * v[c].w;
  ss += __shfl_xor(ss, 1);
  float inv = rsqrtf(ss);
#pragma unroll
  for (int c = 0; c < 8; ++c) {
    float4 a = v[2 * c], b = v[2 * c + 1];
    uint4 o;
    o.x = pack_bf16x2(a.x * inv, a.y * inv);
    o.y = pack_bf16x2(a.z * inv, a.w * inv);
    o.z = pack_bf16x2(b.x * inv, b.y * inv);
    o.w = pack_bf16x2(b.z * inv, b.w * inv);
    ((uint4*)&T[row][0])[(half * 8 + c) ^ (row & 15)] = o;
  }
}

// Persistent-block fused kernel (R8 structure, verified best at 278us).
// R11 change: XCD-locality swizzle. bm0 = b & 7 puts all 64 blocks that
// share a bm-group on ONE XCD (round-robin block->XCD dispatch), so each
// round's 64 KB A-tile is HBM-fetched once and L2-served to the other 63
// blocks — immune to inter-block drift + L3 churn from the write stream
// (R10 counters showed FETCH ~175 MB = A-tiles missing to HBM).
// Waves 0-3 compute+store their own quadrant slabs; ALL barriers lgkm-only
// so tile-t stores stay in flight across tile-(t+1) staging + MFMA.
__global__ __launch_bounds__(256, 2) void sim_kernel(const float* __restrict__ z,
                                                     const float* __restrict__ H,
                                                     float* __restrict__ out) {
  __shared__ __align__(16) unsigned char smem_raw[65536];
  unsigned short (*As)[128] = (unsigned short (*)[128])smem_raw;            // 32 KB (aliased by fS slabs)
  unsigned short (*Bs)[128] = (unsigned short (*)[128])(smem_raw + 32768);  // 32 KB persistent
  float* fS = (float*)smem_raw;   // per-wave slabs: wv*2048 + parity*1024 floats

  int tid = threadIdx.x;
  int b = (int)blockIdx.x;
  int bm0 = b & 7;                // XCD id under round-robin dispatch
  int bn = b >> 3;                // 0..63

  int wv = tid >> 6, lane = tid & 63;
  int wm = (wv >> 1) * 64, wn = (wv & 1) * 64;
  int m16 = lane & 15, g = lane >> 4;
  float* fSw = fS + wv * 2048;

  // ---- stage Bs once (resident for all 8 tiles) ----
  stage_tile(z, bn, Bs, tid);

  for (int t = 0; t < 8; ++t) {
    int bm = bm0 * 8 + t;

    // All waves' slab ds_reads from tile t-1 done -> safe to overwrite the
    // As/slab region. Global stores stay in flight.
    lgkm_barrier();
    stage_tile(z, bm, As, tid);
    lgkm_barrier();   // staging visible to all waves

    // ---- MFMA: wave -> 64x64 quadrant, 4x4 tiles of 16x16x32, K=128 ----
    f32x4 acc[4][4] = {};
#pragma unroll
    for (int kc = 0; kc < 4; ++kc) {
      bf16x8 fa[4], fb[4];
      int chunk = kc * 4 + g;
      int cs = (chunk ^ m16) * 8;   // row bases multiples of 16 -> row&15 == m16
#pragma unroll
      for (int tt = 0; tt < 4; ++tt) {
        fa[tt] = *(const bf16x8*)&As[wm + tt * 16 + m16][cs];
        fb[tt] = *(const bf16x8*)&Bs[wn + tt * 16 + m16][cs];
      }
#pragma unroll
      for (int tm = 0; tm < 4; ++tm)
#pragma unroll
        for (int tn = 0; tn < 4; ++tn)
          acc[tm][tn] = __builtin_amdgcn_mfma_f32_16x16x32_bf16(fa[tm], fb[tn], acc[tm][tn], 0, 0, 0);
    }

    lgkm_barrier();   // all waves' As frag reads done before slab writes

    // ---- epilogue + wave-local slab stores (no cross-wave sync needed) ----
    // C/D layout: col=lane&15, row=g*4+r. Slab = 16 rows x 64 cols fp32,
    // swizzle chunk' = (col>>2) ^ rowInSlab.
#pragma unroll
    for (int tm = 0; tm < 4; ++tm) {
      float* slab = fSw + (tm & 1) * 1024;
#pragma unroll
      for (int tn = 0; tn < 4; ++tn) {
        int colq = tn * 16 + m16;          // quadrant-local col 0..63
        int j = bn * 128 + wn + colq;
        f32x4 c = acc[tm][tn];
#pragma unroll
        for (int r = 0; r < 4; ++r) {
          int rs = g * 4 + r;              // slab row 0..15
          int i = bm * 128 + wm + tm * 16 + rs;
          float s = c[r];
          float val = 0.0f;
          if (i == j) {
            val = 1.0f;
          } else if (s > 0.75f) {
            if (lsh_collide(z, H, i, j)) val = s;   // cold path
          }
          slab[rs * 64 + (((colq >> 2) ^ rs) << 2) + (colq & 3)] = val;
        }
      }
      lgkm_fence();   // slab writes complete before cross-lane readback
      // store slab: 4 instrs, each 4 rows x 256B contiguous segments
#pragma unroll
      for (int it = 0; it < 4; ++it) {
        int rs = it * 4 + g;
        f32x4 v = *(const f32x4*)&slab[rs * 64 + ((m16 ^ rs) << 2)];
        int grow = bm * 128 + wm + tm * 16 + rs;
        *(f32x4*)&out[(size_t)grow * N_NODES + bn * 128 + wn + m16 * 4] = v;
      }
    }
  }
}

extern "C" void kernel_launch(void* const* d_in, const int* in_sizes, int n_in,
                              void* d_out, int out_size, void* d_ws, size_t ws_size,
                              hipStream_t stream) {
  const float* z = (const float*)d_in[0];   // [8192, 128] fp32
  const float* H = (const float*)d_in[1];   // [128, 512] fp32
  // d_in[2] = edge_index, unused by the reference forward.
  float* out = (float*)d_out;               // [8192, 8192] fp32
  (void)d_ws; (void)ws_size;

  sim_kernel<<<512, 256, 0, stream>>>(z, H, out);
}